// Round 8
// baseline (194.698 us; speedup 1.0000x reference)
//
#include <hip/hip_runtime.h>
#include <stdint.h>

// Problem constants (fixed by the reference file)
#define T_TOTAL  4194304          // B*K*N = 8*4*131072
#define NEG_IDLE (-100000000.0f)
#define NEG_FILL (-1000.0f)

#define BLOCK  256
#define EPT    8
#define EPB    (BLOCK * EPT)        // 2048 elements per chunk
#define NCHUNK (T_TOTAL / EPB)      // 2048 chunks
// N = 131072 = 64 * 2048 -> each chunk has one uniform (b,k): bk = chunk >> 6

// Workspace layout:
//   [0 .. 16K)            : sums[2048]   u64 packed (surf lo32, air hi32)
//   [16K .. 16K+1M)       : packed bits, u16 per thread (surf low8 | air<<8)
//   [16K+1M .. 32K+1M)    : prefix[2048] u64 packed exclusive prefix
// Stream order guarantees K1 -> K2 -> K3 visibility; poison needs no init.
#define WS_PACKED_OFF  (NCHUNK * sizeof(unsigned long long))
#define WS_PREFIX_OFF  (WS_PACKED_OFF + (size_t)NCHUNK * BLOCK * sizeof(unsigned short))

typedef unsigned u32x4 __attribute__((ext_vector_type(4)));

// 8 consecutive int32 bool elements -> 8-bit mask (jnp bool arrives as int32).
// Nontemporal loads: mask bytes are read exactly once.
__device__ __forceinline__ unsigned decode8_i32(const u32x4* p) {
    const u32x4 a = __builtin_nontemporal_load(p);
    const u32x4 b = __builtin_nontemporal_load(p + 1);
    return (a.x ? 1u : 0u) | (a.y ? 2u : 0u) | (a.z ? 4u : 0u) | (a.w ? 8u : 0u)
         | (b.x ? 16u : 0u) | (b.y ? 32u : 0u) | (b.z ? 64u : 0u) | (b.w ? 128u : 0u);
}

// ---------------------------------------------------------------------------
// Kernel 1: per-chunk mask popcounts + bit-repack (1 barrier)
// ---------------------------------------------------------------------------
__global__ __launch_bounds__(BLOCK) void reduce_pack_kernel(
    const u32x4* __restrict__ ms,
    const u32x4* __restrict__ ma,
    unsigned long long* __restrict__ sums,
    unsigned short* __restrict__ packed)
{
    const int blk  = blockIdx.x;
    const int tid  = threadIdx.x;
    const int lane = tid & 63;
    const int wave = tid >> 6;
    const size_t e = (size_t)blk * EPB + (size_t)tid * EPT;

    const unsigned bits_s = decode8_i32(ms + (e >> 2));
    const unsigned bits_a = decode8_i32(ma + (e >> 2));
    packed[blk * BLOCK + tid] = (unsigned short)(bits_s | (bits_a << 8));

    unsigned long long v =
        ((unsigned long long)(unsigned)__popc(bits_a) << 32) | (unsigned)__popc(bits_s);
    #pragma unroll
    for (int d = 32; d; d >>= 1) v += __shfl_down(v, d, 64);

    __shared__ unsigned long long w[BLOCK / 64];
    if (lane == 0) w[wave] = v;
    __syncthreads();
    if (tid == 0) sums[blk] = w[0] + w[1] + w[2] + w[3];
}

// ---------------------------------------------------------------------------
// Kernel 2: exclusive scan of sums[2048] -> prefix[2048]. One block, 1024
// threads, 2 entries/thread; wave shfl scan + 16 wave-totals in LDS.
// ---------------------------------------------------------------------------
__global__ __launch_bounds__(1024) void scan_kernel(
    const unsigned long long* __restrict__ sums,
    unsigned long long* __restrict__ prefix)
{
    const int tid  = threadIdx.x;
    const int lane = tid & 63;
    const int wave = tid >> 6;

    const unsigned long long a = sums[2 * tid];
    const unsigned long long b = sums[2 * tid + 1];
    const unsigned long long s = a + b;

    unsigned long long incl = s;
    #pragma unroll
    for (int d = 1; d < 64; d <<= 1) {
        unsigned long long t = __shfl_up(incl, d, 64);
        if (lane >= d) incl += t;
    }

    __shared__ unsigned long long wtot[16];
    if (lane == 63) wtot[wave] = incl;
    __syncthreads();
    unsigned long long prior = 0;
    #pragma unroll
    for (int w = 0; w < 16; ++w)
        if (w < wave) prior += wtot[w];

    const unsigned long long excl = prior + (incl - s);
    prefix[2 * tid]     = excl;
    prefix[2 * tid + 1] = excl + a;
}

// ---------------------------------------------------------------------------
// Kernel 3: role-split scatter with LDS-staged contiguous gather ranges.
//   role 0: rgb (bits_s), role 1: logits_surface (bits_s), role 2: la (bits_a)
// Block prefix comes from prefix[blk] (uniform -> s_load, 1 line/block —
// replaces the splintered 16KB/block reduce, r7's limiter). Monotone indices
// => block's sources are contiguous: stage them into LDS with coalesced
// loads (each line touched ONCE vs 8-24x re-touch of direct gathers), then
// redistribute from LDS. Plain cached stores (NT caused 2x write amp, r5).
// ---------------------------------------------------------------------------
__global__ __launch_bounds__(BLOCK) void scatter_kernel(
    const float* __restrict__ rgb,
    const float* __restrict__ ls,
    const float* __restrict__ la,
    const unsigned long long* __restrict__ prefix,
    const unsigned short* __restrict__ packed,
    const float* __restrict__ idle_states,
    float* __restrict__ out)
{
    __shared__ float stage[3 * EPB];     // 24 KB worst case (role 0)
    __shared__ int   wtot[BLOCK / 64];

    const int bid  = blockIdx.x;
    const int role = bid >> 11;            // /NCHUNK: 0=rgb 1=ls 2=la
    const int blk  = bid & (NCHUNK - 1);
    const int tid  = threadIdx.x;
    const int lane = tid & 63;
    const int wave = tid >> 6;
    const size_t base = (size_t)blk * EPB + (size_t)tid * EPT;

    const unsigned pw   = packed[blk * BLOCK + tid];
    const unsigned bits = (role == 2) ? (pw >> 8) : (pw & 0xffu);
    const int c = __popc(bits);

    // uniform per block -> scalar load, single L2 line
    const unsigned long long pre64 = prefix[blk];
    const int S0 = (role == 2) ? (int)(pre64 >> 32) : (int)(pre64 & 0xffffffffull);

    // ---- 32-bit wave inclusive scan of per-thread count ----
    int incl = c;
    #pragma unroll
    for (int d = 1; d < 64; d <<= 1) {
        const int t = __shfl_up(incl, d, 64);
        if (lane >= d) incl += t;
    }
    int excl = incl - c;

    if (lane == 63) wtot[wave] = incl;
    __syncthreads();
    #pragma unroll
    for (int w = 0; w < BLOCK / 64; ++w)
        if (w < wave) excl += wtot[w];
    const int tot = wtot[0] + wtot[1] + wtot[2] + wtot[3];   // block count

    // ---- coalesced staging of the block's contiguous source range ----
    if (role == 0) {
        const float* src = rgb + (size_t)3 * S0;
        const int n = 3 * tot;
        for (int i = tid; i < n; i += BLOCK) stage[i] = src[i];
    } else {
        const float* src = ((role == 1) ? ls : la) + S0;
        for (int i = tid; i < tot; i += BLOCK) stage[i] = src[i];
    }
    __syncthreads();

    // block-local per-element compact offsets (branch-free)
    int loc[EPT];
    #pragma unroll
    for (int j = 0; j < EPT; ++j)
        loc[j] = excl + __popc(bits & ((1u << j) - 1u));

    const float idle      = idle_states[blk >> 6];   // uniform per block
    const float scale     = 1.0f - idle;
    const float idle_term = idle * NEG_IDLE;

    if (role == 0) {
        float r[3 * EPT];
        #pragma unroll
        for (int j = 0; j < EPT; ++j) {
            r[3 * j + 0] = stage[3 * loc[j] + 0];
            r[3 * j + 1] = stage[3 * loc[j] + 1];
            r[3 * j + 2] = stage[3 * loc[j] + 2];
        }
        #pragma unroll
        for (int j = 0; j < EPT; ++j) {
            const bool bs = (bits >> j) & 1u;
            r[3 * j + 0] = bs ? r[3 * j + 0] * scale : 0.0f;
            r[3 * j + 1] = bs ? r[3 * j + 1] * scale : 0.0f;
            r[3 * j + 2] = bs ? r[3 * j + 2] * scale : 0.0f;
        }
        float4* dst = (float4*)(out + base * 3);                 // 96 B/thread
        #pragma unroll
        for (int j = 0; j < 6; ++j) dst[j] = ((const float4*)r)[j];
    } else {
        float v[EPT];
        #pragma unroll
        for (int j = 0; j < EPT; ++j) v[j] = stage[loc[j]];
        #pragma unroll
        for (int j = 0; j < EPT; ++j) {
            const bool b = (bits >> j) & 1u;
            v[j] = b ? (v[j] * scale + idle_term) : NEG_FILL;
        }
        float4* dst = (float4*)(out + (size_t)(2 + role) * T_TOTAL + base);
        dst[0] = ((const float4*)v)[0];
        dst[1] = ((const float4*)v)[1];
    }
}

// ---------------------------------------------------------------------------
extern "C" void kernel_launch(void* const* d_in, const int* in_sizes, int n_in,
                              void* d_out, int out_size, void* d_ws, size_t ws_size,
                              hipStream_t stream) {
    const float* rgb  = (const float*)d_in[0];
    const float* ls   = (const float*)d_in[1];
    const float* la   = (const float*)d_in[2];
    const u32x4* ms   = (const u32x4*)d_in[3];   // jnp bool -> int32 on device
    const u32x4* ma   = (const u32x4*)d_in[4];
    const float* idle = (const float*)d_in[5];
    float* out = (float*)d_out;

    unsigned long long* sums   = (unsigned long long*)d_ws;
    unsigned short*     packed = (unsigned short*)((uint8_t*)d_ws + WS_PACKED_OFF);
    unsigned long long* prefix = (unsigned long long*)((uint8_t*)d_ws + WS_PREFIX_OFF);

    reduce_pack_kernel<<<NCHUNK, BLOCK, 0, stream>>>(ms, ma, sums, packed);
    scan_kernel<<<1, 1024, 0, stream>>>(sums, prefix);
    scatter_kernel<<<3 * NCHUNK, BLOCK, 0, stream>>>(rgb, ls, la, prefix, packed,
                                                     idle, out);
}

// Round 9
// 188.284 us; speedup vs baseline: 1.0341x; 1.0341x over previous
//
#include <hip/hip_runtime.h>
#include <stdint.h>

// Problem constants (fixed by the reference file)
#define T_TOTAL  4194304          // B*K*N = 8*4*131072
#define NEG_IDLE (-100000000.0f)
#define NEG_FILL (-1000.0f)

#define BLOCK  256
#define EPT    8
#define EPB    (BLOCK * EPT)        // 2048 elements per chunk
#define NCHUNK (T_TOTAL / EPB)      // 2048 chunks
// N = 131072 = 64 * 2048 -> each chunk has one uniform (b,k): bk = chunk >> 6

// Workspace layout:
//   [0 .. 16K)            : sums[2048]   u64 packed (surf lo32, air hi32)
//   [16K .. 16K+1M)       : packed bits, u16 per thread (surf low8 | air<<8)
//   [16K+1M .. 32K+1M)    : prefix[2048] u64 packed exclusive prefix
// Stream order guarantees K1 -> K2 -> K3 visibility; poison needs no init.
#define WS_PACKED_OFF  (NCHUNK * sizeof(unsigned long long))
#define WS_PREFIX_OFF  (WS_PACKED_OFF + (size_t)NCHUNK * BLOCK * sizeof(unsigned short))

typedef unsigned u32x4 __attribute__((ext_vector_type(4)));
// 4-byte-aligned float4: gfx950 global_load_dwordx4 only needs dword alignment
typedef float f4u __attribute__((ext_vector_type(4), aligned(4)));

// 8 consecutive int32 bool elements -> 8-bit mask (jnp bool arrives as int32).
// Nontemporal loads: mask bytes are read exactly once.
__device__ __forceinline__ unsigned decode8_i32(const u32x4* p) {
    const u32x4 a = __builtin_nontemporal_load(p);
    const u32x4 b = __builtin_nontemporal_load(p + 1);
    return (a.x ? 1u : 0u) | (a.y ? 2u : 0u) | (a.z ? 4u : 0u) | (a.w ? 8u : 0u)
         | (b.x ? 16u : 0u) | (b.y ? 32u : 0u) | (b.z ? 64u : 0u) | (b.w ? 128u : 0u);
}

// Select element pc (0..7) from the concatenation [a.x..a.w, b.x..b.w].
// Compiles to ~7 v_cndmask — trades idle VALU for 8 scalar gather dwords.
__device__ __forceinline__ float pick8(const f4u a, const f4u b, int pc) {
    const float lo = (pc & 1) ? ((pc & 2) ? a.w : a.y) : ((pc & 2) ? a.z : a.x);
    const float hi = (pc & 1) ? ((pc & 2) ? b.w : b.y) : ((pc & 2) ? b.z : b.x);
    return (pc & 4) ? hi : lo;
}

// ---------------------------------------------------------------------------
// Kernel 1: per-chunk mask popcounts + bit-repack (1 barrier)
// ---------------------------------------------------------------------------
__global__ __launch_bounds__(BLOCK) void reduce_pack_kernel(
    const u32x4* __restrict__ ms,
    const u32x4* __restrict__ ma,
    unsigned long long* __restrict__ sums,
    unsigned short* __restrict__ packed)
{
    const int blk  = blockIdx.x;
    const int tid  = threadIdx.x;
    const int lane = tid & 63;
    const int wave = tid >> 6;
    const size_t e = (size_t)blk * EPB + (size_t)tid * EPT;

    const unsigned bits_s = decode8_i32(ms + (e >> 2));
    const unsigned bits_a = decode8_i32(ma + (e >> 2));
    packed[blk * BLOCK + tid] = (unsigned short)(bits_s | (bits_a << 8));

    unsigned long long v =
        ((unsigned long long)(unsigned)__popc(bits_a) << 32) | (unsigned)__popc(bits_s);
    #pragma unroll
    for (int d = 32; d; d >>= 1) v += __shfl_down(v, d, 64);

    __shared__ unsigned long long w[BLOCK / 64];
    if (lane == 0) w[wave] = v;
    __syncthreads();
    if (tid == 0) sums[blk] = w[0] + w[1] + w[2] + w[3];
}

// ---------------------------------------------------------------------------
// Kernel 2: exclusive scan of sums[2048] -> prefix[2048]. One block, 1024
// threads, 2 entries/thread; wave shfl scan + 16 wave-totals in LDS.
// ---------------------------------------------------------------------------
__global__ __launch_bounds__(1024) void scan_kernel(
    const unsigned long long* __restrict__ sums,
    unsigned long long* __restrict__ prefix)
{
    const int tid  = threadIdx.x;
    const int lane = tid & 63;
    const int wave = tid >> 6;

    const unsigned long long a = sums[2 * tid];
    const unsigned long long b = sums[2 * tid + 1];
    const unsigned long long s = a + b;

    unsigned long long incl = s;
    #pragma unroll
    for (int d = 1; d < 64; d <<= 1) {
        unsigned long long t = __shfl_up(incl, d, 64);
        if (lane >= d) incl += t;
    }

    __shared__ unsigned long long wtot[16];
    if (lane == 63) wtot[wave] = incl;
    __syncthreads();
    unsigned long long prior = 0;
    #pragma unroll
    for (int w = 0; w < 16; ++w)
        if (w < wave) prior += wtot[w];

    const unsigned long long excl = prior + (incl - s);
    prefix[2 * tid]     = excl;
    prefix[2 * tid + 1] = excl + a;
}

// ---------------------------------------------------------------------------
// Kernel 3: combined scatter (r4 structure — the best measured).
// Block prefix from prefix[blk] (uniform s_load; replaces splintered 16KB
// reduce, ~4.5us saved per r7->r8 A/B). rgb: direct scalar gathers (L3
// absorbs re-touches). ls/la: thread's <=8 gathered values are CONTIGUOUS in
// [idx0, idx0+8) => two dwordx4 loads + cndmask pick tree instead of 8
// scalar gathers each. Plain cached stores (NT stores = 2x write amp, r5).
// ---------------------------------------------------------------------------
__global__ __launch_bounds__(BLOCK) void scatter_kernel(
    const float* __restrict__ rgb,
    const float* __restrict__ ls,
    const float* __restrict__ la,
    const unsigned long long* __restrict__ prefix,
    const unsigned short* __restrict__ packed,
    const float* __restrict__ idle_states,
    float* __restrict__ out)
{
    const int blk  = blockIdx.x;
    const int tid  = threadIdx.x;
    const int lane = tid & 63;
    const int wave = tid >> 6;
    const size_t base = (size_t)blk * EPB + (size_t)tid * EPT;

    // ---- masks ----
    const unsigned p = packed[blk * BLOCK + tid];
    const unsigned bits_s = p & 0xffu;
    const unsigned bits_a = p >> 8;

    // ---- block prefix: uniform -> scalar load ----
    const unsigned long long pre = prefix[blk];

    // ---- wave inclusive scan of packed (air<<32 | surf) counts ----
    const unsigned long long pk =
        ((unsigned long long)(unsigned)__popc(bits_a) << 32) | (unsigned)__popc(bits_s);
    unsigned long long incl = pk;
    #pragma unroll
    for (int d = 1; d < 64; d <<= 1) {
        unsigned long long t = __shfl_up(incl, d, 64);
        if (lane >= d) incl += t;
    }
    unsigned long long excl = incl - pk;

    __shared__ unsigned long long wtot[BLOCK / 64];
    if (lane == 63) wtot[wave] = incl;
    __syncthreads();
    #pragma unroll
    for (int w = 0; w < BLOCK / 64; ++w)
        if (w < wave) excl += wtot[w];

    const int idx_s0 = (int)((pre + excl) & 0xffffffffULL);
    const int idx_a0 = (int)((pre + excl) >> 32);

    // ---- rgb: per-element indices (branch-free), direct gathers ----
    int is_[EPT];
    #pragma unroll
    for (int j = 0; j < EPT; ++j)
        is_[j] = idx_s0 + __popc(bits_s & ((1u << j) - 1u));

    float r[3 * EPT];
    #pragma unroll
    for (int j = 0; j < EPT; ++j) {
        const float* rp = rgb + (size_t)is_[j] * 3;   // always in-bounds
        r[3 * j + 0] = rp[0];
        r[3 * j + 1] = rp[1];
        r[3 * j + 2] = rp[2];
    }

    // ---- logits: contiguous window loads (idx0..idx0+8 always within [0,T)) ----
    const f4u* pls_src = (const f4u*)(ls + idx_s0);
    const f4u* pla_src = (const f4u*)(la + idx_a0);
    const f4u ls_a = pls_src[0], ls_b = pls_src[1];
    const f4u la_a = pla_src[0], la_b = pla_src[1];

    // ---- select/scale ----
    const float idle      = idle_states[blk >> 6];   // uniform per block
    const float scale     = 1.0f - idle;
    const float idle_term = idle * NEG_IDLE;

    float sv[EPT], av[EPT];
    #pragma unroll
    for (int j = 0; j < EPT; ++j) {
        const bool bs = (bits_s >> j) & 1u;
        const bool ba = (bits_a >> j) & 1u;
        const int pcs = __popc(bits_s & ((1u << j) - 1u));
        const int pca = __popc(bits_a & ((1u << j) - 1u));
        const float lsv = pick8(ls_a, ls_b, pcs);
        const float lav = pick8(la_a, la_b, pca);
        r[3 * j + 0] = bs ? r[3 * j + 0] * scale : 0.0f;
        r[3 * j + 1] = bs ? r[3 * j + 1] * scale : 0.0f;
        r[3 * j + 2] = bs ? r[3 * j + 2] * scale : 0.0f;
        sv[j] = bs ? (lsv * scale + idle_term) : NEG_FILL;
        av[j] = ba ? (lav * scale + idle_term) : NEG_FILL;
    }

    // ---- vectorized stores (plain/cached: L2 merges into full lines) ----
    float4* prgb = (float4*)(out + base * 3);                    // 96 B/thread
    #pragma unroll
    for (int j = 0; j < 6; ++j) prgb[j] = ((const float4*)r)[j];

    float4* pls = (float4*)(out + (size_t)3 * T_TOTAL + base);   // 32 B/thread
    pls[0] = ((const float4*)sv)[0];
    pls[1] = ((const float4*)sv)[1];

    float4* pla = (float4*)(out + (size_t)4 * T_TOTAL + base);
    pla[0] = ((const float4*)av)[0];
    pla[1] = ((const float4*)av)[1];
}

// ---------------------------------------------------------------------------
extern "C" void kernel_launch(void* const* d_in, const int* in_sizes, int n_in,
                              void* d_out, int out_size, void* d_ws, size_t ws_size,
                              hipStream_t stream) {
    const float* rgb  = (const float*)d_in[0];
    const float* ls   = (const float*)d_in[1];
    const float* la   = (const float*)d_in[2];
    const u32x4* ms   = (const u32x4*)d_in[3];   // jnp bool -> int32 on device
    const u32x4* ma   = (const u32x4*)d_in[4];
    const float* idle = (const float*)d_in[5];
    float* out = (float*)d_out;

    unsigned long long* sums   = (unsigned long long*)d_ws;
    unsigned short*     packed = (unsigned short*)((uint8_t*)d_ws + WS_PACKED_OFF);
    unsigned long long* prefix = (unsigned long long*)((uint8_t*)d_ws + WS_PREFIX_OFF);

    reduce_pack_kernel<<<NCHUNK, BLOCK, 0, stream>>>(ms, ma, sums, packed);
    scan_kernel<<<1, 1024, 0, stream>>>(sums, prefix);
    scatter_kernel<<<NCHUNK, BLOCK, 0, stream>>>(rgb, ls, la, prefix, packed,
                                                 idle, out);
}